// Round 8
// baseline (1034.253 us; speedup 1.0000x reference)
//
#include <hip/hip_runtime.h>

#define NODES   30000
#define E0N     480000
#define ETOT    510000   // E0N + NODES self loops
#define D0      100
#define WDIM    300      // H*F = 3*100
#define NW      600      // dual output width
#define KPAD    320      // padded K for frag buffers
#define NEG     0.2f

typedef __bf16 bf16x8 __attribute__((ext_vector_type(8)));
typedef float  f32x4  __attribute__((ext_vector_type(4)));

// ---------------- CSR build ----------------
__global__ void count_edges(const int* __restrict__ ei, int* __restrict__ counts) {
    int e = blockIdx.x * 256 + threadIdx.x;
    if (e >= ETOT) return;
    int d = (e < E0N) ? ei[E0N + e] : (e - E0N);
    atomicAdd(&counts[d], 1);
}

__global__ __launch_bounds__(1024) void scan_kernel(const int* __restrict__ counts,
                                                    int* __restrict__ offsets, int n) {
    __shared__ int lds[1024];
    const int CH = 32;
    int t = threadIdx.x;
    int base = t * CH;
    int loc[CH];
    int sum = 0;
    #pragma unroll
    for (int i = 0; i < CH; i++) {
        int v = (base + i < n) ? counts[base + i] : 0;
        loc[i] = sum;
        sum += v;
    }
    lds[t] = sum;
    __syncthreads();
    for (int off = 1; off < 1024; off <<= 1) {
        int v = (t >= off) ? lds[t - off] : 0;
        __syncthreads();
        lds[t] += v;
        __syncthreads();
    }
    int ex = (t == 0) ? 0 : lds[t - 1];
    #pragma unroll
    for (int i = 0; i < CH; i++) {
        int idx = base + i;
        if (idx < n) offsets[idx] = ex + loc[i];
    }
    if (t == 0) offsets[n] = lds[1023];
}

__global__ void scatter_edges(const int* __restrict__ ei, const int* __restrict__ offsets,
                              int* __restrict__ cursor, int* __restrict__ csr_src) {
    int e = blockIdx.x * 256 + threadIdx.x;
    if (e >= ETOT) return;
    int s, d;
    if (e < E0N) { s = ei[e]; d = ei[E0N + e]; }
    else         { s = e - E0N; d = s; }
    int pos = offsets[d] + atomicAdd(&cursor[d], 1);
    csr_src[pos] = s;
}

// ---------------- B fragment pre-split (hi/lo bf16, MFMA-fragment-linear) ----
__global__ void make_bfrag(const float* __restrict__ Bl, const float* __restrict__ Br,
                           bf16x8* __restrict__ out, int K, int ksteps) {
    int t = blockIdx.x * 256 + threadIdx.x;
    int total = ksteps * 40 * 64;
    if (t >= total) return;
    int lane = t & 63;
    int n16  = (t >> 6) % 40;
    int s    = t / (64 * 40);
    int c = n16 * 16 + (lane & 15);
    union { bf16x8 v; __bf16 e[8]; } hi, lo;
    #pragma unroll
    for (int j = 0; j < 8; j++) {
        int k = s * 32 + ((lane >> 4) * 8) + j;
        float x = 0.f;
        if (k < K && c < NW)
            x = (c < WDIM) ? Bl[(size_t)k * WDIM + c] : Br[(size_t)k * WDIM + c - WDIM];
        __bf16 h = (__bf16)x;
        hi.e[j] = h;
        lo.e[j] = (__bf16)(x - (float)h);
    }
    size_t base = ((size_t)(s * 40 + n16) * 2) * 64 + lane;
    out[base]      = hi.v;
    out[base + 64] = lo.v;
}

// ---------------- layer-0 MFMA GEMM: A = emb[xmap[row]] (f32, inline split) ----
__global__ __launch_bounds__(256) void gemm_emb(
    const float* __restrict__ A, const int* __restrict__ xmap,
    const bf16x8* __restrict__ Bfrag,
    const float* __restrict__ bl, const float* __restrict__ br,
    float* __restrict__ Cl, float* __restrict__ Cr,
    int M, int K, int ksteps) {

    __shared__ bf16x8 Alds[8][2][64];
    __shared__ bf16x8 Blds[8][2][64];

    int id = blockIdx.x;
    int mb = (id & 7) + 8 * (id / 40);
    int cb = (id >> 3) % 5;
    if (mb >= 235) return;

    int tid  = threadIdx.x;
    int lane = tid & 63;
    int wid  = tid >> 6;
    int wm = wid >> 1, wn = wid & 1;
    int row0 = mb * 128;

    f32x4 acc[4][4] = {};

    for (int s = 0; s < ksteps; s++) {
        int kt = s * 32;
        #pragma unroll
        for (int u0 = 0; u0 < 2; u0++) {
            int u = u0 * 256 + tid;
            int m16  = u >> 6;
            int slot = u & 63;
            int kh = slot >> 4, rl = slot & 15;
            int gr = row0 + m16 * 16 + rl;
            int gc = kt + kh * 8;
            float4 v0 = make_float4(0.f,0.f,0.f,0.f), v1 = v0;
            if (gr < M) {
                int ar = xmap[gr];
                const float* ap = A + (size_t)ar * K + gc;
                if (gc + 4 <= K) v0 = *(const float4*)ap;
                if (gc + 8 <= K) v1 = *(const float4*)(ap + 4);
            }
            union { bf16x8 v; __bf16 e[8]; } hi, lo;
            const float* xs0 = (const float*)&v0;
            const float* xs1 = (const float*)&v1;
            #pragma unroll
            for (int j = 0; j < 8; j++) {
                float x = (j < 4) ? xs0[j] : xs1[j - 4];
                __bf16 h = (__bf16)x;
                hi.e[j] = h;
                lo.e[j] = (__bf16)(x - (float)h);
            }
            Alds[m16][0][slot] = hi.v;
            Alds[m16][1][slot] = lo.v;
        }
        {
            const float4* bsrc = (const float4*)(Bfrag + ((size_t)(s * 40 + cb * 8) * 2) * 64);
            float4* bdst = (float4*)&Blds[0][0][0];
            #pragma unroll
            for (int c = 0; c < 4; c++)
                bdst[c * 256 + tid] = bsrc[c * 256 + tid];
        }
        __syncthreads();

        bf16x8 af[4][2], bfr[4][2];
        #pragma unroll
        for (int m = 0; m < 4; m++) {
            af[m][0] = Alds[wm * 4 + m][0][lane];
            af[m][1] = Alds[wm * 4 + m][1][lane];
        }
        #pragma unroll
        for (int n = 0; n < 4; n++) {
            bfr[n][0] = Blds[wn * 4 + n][0][lane];
            bfr[n][1] = Blds[wn * 4 + n][1][lane];
        }
        #pragma unroll
        for (int m = 0; m < 4; m++)
            #pragma unroll
            for (int n = 0; n < 4; n++) {
                acc[m][n] = __builtin_amdgcn_mfma_f32_16x16x32_bf16(af[m][1], bfr[n][0], acc[m][n], 0, 0, 0);
                acc[m][n] = __builtin_amdgcn_mfma_f32_16x16x32_bf16(af[m][0], bfr[n][1], acc[m][n], 0, 0, 0);
                acc[m][n] = __builtin_amdgcn_mfma_f32_16x16x32_bf16(af[m][0], bfr[n][0], acc[m][n], 0, 0, 0);
            }
        __syncthreads();
    }

    int r0 = row0 + wm * 64;
    int c0 = cb * 128 + wn * 64;
    #pragma unroll
    for (int m = 0; m < 4; m++)
        #pragma unroll
        for (int n = 0; n < 4; n++) {
            #pragma unroll
            for (int reg = 0; reg < 4; reg++) {
                int gr = r0 + m * 16 + (lane >> 4) * 4 + reg;
                int gc = c0 + n * 16 + (lane & 15);
                if (gr < M && gc < NW) {
                    bool left = gc < WDIM;
                    int cc = left ? gc : gc - WDIM;
                    float v = acc[m][n][reg] + (left ? bl[cc] : br[cc]);
                    (left ? Cl : Cr)[(size_t)gr * WDIM + cc] = v;
                }
            }
        }
}

// ---------------- layers 1-4 MFMA GEMM: A pre-split (ahi/alo [M][320] bf16) ----
__global__ __launch_bounds__(256) void gemm_frag(
    const ushort* __restrict__ ahi, const ushort* __restrict__ alo,
    const bf16x8* __restrict__ Bfrag,
    const float* __restrict__ bl, const float* __restrict__ br,
    float* __restrict__ Cl, float* __restrict__ Cr, int M) {

    __shared__ bf16x8 Alds[8][2][64];
    __shared__ bf16x8 Blds[8][2][64];

    int id = blockIdx.x;
    int mb = (id & 7) + 8 * (id / 40);
    int cb = (id >> 3) % 5;
    if (mb >= 235) return;

    int tid  = threadIdx.x;
    int lane = tid & 63;
    int wid  = tid >> 6;
    int wm = wid >> 1, wn = wid & 1;
    int row0 = mb * 128;

    f32x4 acc[4][4] = {};

    for (int s = 0; s < 10; s++) {
        int kt = s * 32;
        // A stage: pure 16B copies (rows >= M read slack; masked at store)
        #pragma unroll
        for (int u0 = 0; u0 < 2; u0++) {
            int u = u0 * 256 + tid;
            int m16  = u >> 6;
            int slot = u & 63;
            size_t off = (size_t)(row0 + m16 * 16 + (slot & 15)) * KPAD + kt + (slot >> 4) * 8;
            Alds[m16][0][slot] = *(const bf16x8*)(ahi + off);
            Alds[m16][1][slot] = *(const bf16x8*)(alo + off);
        }
        {
            const float4* bsrc = (const float4*)(Bfrag + ((size_t)(s * 40 + cb * 8) * 2) * 64);
            float4* bdst = (float4*)&Blds[0][0][0];
            #pragma unroll
            for (int c = 0; c < 4; c++)
                bdst[c * 256 + tid] = bsrc[c * 256 + tid];
        }
        __syncthreads();

        bf16x8 af[4][2], bfr[4][2];
        #pragma unroll
        for (int m = 0; m < 4; m++) {
            af[m][0] = Alds[wm * 4 + m][0][lane];
            af[m][1] = Alds[wm * 4 + m][1][lane];
        }
        #pragma unroll
        for (int n = 0; n < 4; n++) {
            bfr[n][0] = Blds[wn * 4 + n][0][lane];
            bfr[n][1] = Blds[wn * 4 + n][1][lane];
        }
        #pragma unroll
        for (int m = 0; m < 4; m++)
            #pragma unroll
            for (int n = 0; n < 4; n++) {
                acc[m][n] = __builtin_amdgcn_mfma_f32_16x16x32_bf16(af[m][1], bfr[n][0], acc[m][n], 0, 0, 0);
                acc[m][n] = __builtin_amdgcn_mfma_f32_16x16x32_bf16(af[m][0], bfr[n][1], acc[m][n], 0, 0, 0);
                acc[m][n] = __builtin_amdgcn_mfma_f32_16x16x32_bf16(af[m][0], bfr[n][0], acc[m][n], 0, 0, 0);
            }
        __syncthreads();
    }

    int r0 = row0 + wm * 64;
    int c0 = cb * 128 + wn * 64;
    #pragma unroll
    for (int m = 0; m < 4; m++)
        #pragma unroll
        for (int n = 0; n < 4; n++) {
            #pragma unroll
            for (int reg = 0; reg < 4; reg++) {
                int gr = r0 + m * 16 + (lane >> 4) * 4 + reg;
                int gc = c0 + n * 16 + (lane & 15);
                if (gr < M && gc < NW) {
                    bool left = gc < WDIM;
                    int cc = left ? gc : gc - WDIM;
                    float v = acc[m][n][reg] + (left ? bl[cc] : br[cc]);
                    (left ? Cl : Cr)[(size_t)gr * WDIM + cc] = v;
                }
            }
        }
}

// ---------------- fused GAT: wave-per-node, 2-edge ILP, float2 slots ----
// float2 slot j: i = lane + 64*j (i<150 valid), f = 2i,2i+1; head uniform per float2.
// Softmax state packed by lane residue r=lane&3 (r=0:h0 r=1:h1 r=2:h2).
// Output: frag mode writes hi/lo bf16 [node][320] (zero-padded); else flat f32.
__global__ __launch_bounds__(256) void gat_edge_agg(
    const float* __restrict__ xl, const float* __restrict__ xr,
    const int* __restrict__ offsets, const int* __restrict__ csr_src,
    const float* __restrict__ att, const float* __restrict__ bias,
    float* __restrict__ fout, ushort* __restrict__ ahi, ushort* __restrict__ alo,
    int write_frag) {
    int node = (blockIdx.x * 256 + threadIdx.x) >> 6;
    int lane = threadIdx.x & 63;
    if (node >= NODES) return;
    int r = lane & 3;
    bool c0 = lane < 50;   // j0: head0 else head1
    bool c1 = lane < 36;   // j1: head1 else head2

    float2 aw2[3], xr2[3];
    const float2* xrrow = (const float2*)(xr + (size_t)node * WDIM);
    #pragma unroll
    for (int j = 0; j < 3; j++) {
        int i = lane + 64 * j;
        if (i < 150) { aw2[j].x = att[2 * i]; aw2[j].y = att[2 * i + 1]; }
        else         { aw2[j].x = 0.f;        aw2[j].y = 0.f; }
        xr2[j] = xrrow[i];   // unguarded: slack lands on benign data
    }

    float mq = -1e38f, sq = 0.f;
    float2 acc2[3] = {};

    int beg = offsets[node], end = offsets[node + 1];
    for (int i = beg; i < end; i += 2) {
        bool act_b = (i + 1) < end;
        int sa = csr_src[i];
        int sb = csr_src[act_b ? i + 1 : i];
        const float2* ra = (const float2*)(xl + (size_t)sa * WDIM);
        const float2* rb = (const float2*)(xl + (size_t)sb * WDIM);
        float2 va[3], vb[3];
        #pragma unroll
        for (int j = 0; j < 3; j++) {
            va[j] = ra[lane + 64 * j];
            vb[j] = rb[lane + 64 * j];
        }
        float qa[3], qb[3];
        #pragma unroll
        for (int j = 0; j < 3; j++) {
            float tax = va[j].x + xr2[j].x; tax = fmaxf(tax, NEG * tax);
            float tay = va[j].y + xr2[j].y; tay = fmaxf(tay, NEG * tay);
            float tbx = vb[j].x + xr2[j].x; tbx = fmaxf(tbx, NEG * tbx);
            float tby = vb[j].y + xr2[j].y; tby = fmaxf(tby, NEG * tby);
            qa[j] = tax * aw2[j].x + tay * aw2[j].y;
            qb[j] = tbx * aw2[j].x + tby * aw2[j].y;
        }
        float pa0 = c0 ? qa[0] : 0.f;
        float pa1 = (c0 ? 0.f : qa[0]) + (c1 ? qa[1] : 0.f);
        float pa2 = (c1 ? 0.f : qa[1]) + qa[2];
        float pb0 = c0 ? qb[0] : 0.f;
        float pb1 = (c0 ? 0.f : qb[0]) + (c1 ? qb[1] : 0.f);
        float pb2 = (c1 ? 0.f : qb[1]) + qb[2];

        // stages 1,2 on all 6 partials; pack by residue; stages 4..32 on 2
        pa0 += __shfl_xor(pa0, 1, 64); pa1 += __shfl_xor(pa1, 1, 64); pa2 += __shfl_xor(pa2, 1, 64);
        pb0 += __shfl_xor(pb0, 1, 64); pb1 += __shfl_xor(pb1, 1, 64); pb2 += __shfl_xor(pb2, 1, 64);
        pa0 += __shfl_xor(pa0, 2, 64); pa1 += __shfl_xor(pa1, 2, 64); pa2 += __shfl_xor(pa2, 2, 64);
        pb0 += __shfl_xor(pb0, 2, 64); pb1 += __shfl_xor(pb1, 2, 64); pb2 += __shfl_xor(pb2, 2, 64);
        float sqa = (r == 1) ? pa1 : ((r == 2) ? pa2 : pa0);
        float sqb = (r == 1) ? pb1 : ((r == 2) ? pb2 : pb0);
        sqa += __shfl_xor(sqa, 4, 64);  sqb += __shfl_xor(sqb, 4, 64);
        sqa += __shfl_xor(sqa, 8, 64);  sqb += __shfl_xor(sqb, 8, 64);
        sqa += __shfl_xor(sqa, 16, 64); sqb += __shfl_xor(sqb, 16, 64);
        sqa += __shfl_xor(sqa, 32, 64); sqb += __shfl_xor(sqb, 32, 64);
        if (!act_b) sqb = -3e38f;

        // defer-rescale (THR=8), packed state
        float hiq = fmaxf(sqa, sqb);
        if (__any(hiq > mq + 8.f)) {
            float nmq = fmaxf(mq, hiq);
            float eq = __expf(mq - nmq);
            sq *= eq;
            float e0 = __shfl(eq, 0, 64), e1 = __shfl(eq, 1, 64), e2 = __shfl(eq, 2, 64);
            float ej0 = c0 ? e0 : e1, ej1 = c1 ? e1 : e2;
            acc2[0].x *= ej0; acc2[0].y *= ej0;
            acc2[1].x *= ej1; acc2[1].y *= ej1;
            acc2[2].x *= e2;  acc2[2].y *= e2;
            mq = nmq;
        }
        float cqa = __expf(sqa - mq), cqb = __expf(sqb - mq);
        sq += cqa + cqb;
        float ca0 = __shfl(cqa, 0, 64), ca1 = __shfl(cqa, 1, 64), ca2 = __shfl(cqa, 2, 64);
        float cb0 = __shfl(cqb, 0, 64), cb1 = __shfl(cqb, 1, 64), cb2 = __shfl(cqb, 2, 64);
        float caj[3] = { c0 ? ca0 : ca1, c1 ? ca1 : ca2, ca2 };
        float cbj[3] = { c0 ? cb0 : cb1, c1 ? cb1 : cb2, cb2 };
        #pragma unroll
        for (int j = 0; j < 3; j++) {
            acc2[j].x = fmaf(caj[j], va[j].x, acc2[j].x);
            acc2[j].y = fmaf(caj[j], va[j].y, acc2[j].y);
            acc2[j].x = fmaf(cbj[j], vb[j].x, acc2[j].x);
            acc2[j].y = fmaf(cbj[j], vb[j].y, acc2[j].y);
        }
    }

    float iq = 1.f / sq;
    float i0 = __shfl(iq, 0, 64), i1 = __shfl(iq, 1, 64), i2 = __shfl(iq, 2, 64);
    float isel[3] = { c0 ? i0 : i1, c1 ? i1 : i2, i2 };

    if (write_frag) {
        #pragma unroll
        for (int j = 0; j < 3; j++) {
            int i = lane + 64 * j;
            if (i < 160) {
                float ox = 0.f, oy = 0.f;
                if (i < 150) {
                    float bx = bias[2 * i], by = bias[2 * i + 1];
                    ox = fmaxf(acc2[j].x * isel[j] + bx, 0.f);
                    oy = fmaxf(acc2[j].y * isel[j] + by, 0.f);
                }
                __bf16 hx = (__bf16)ox, hy = (__bf16)oy;
                __bf16 lx = (__bf16)(ox - (float)hx), ly = (__bf16)(oy - (float)hy);
                ushort2 hv, lv;
                hv.x = *(ushort*)&hx; hv.y = *(ushort*)&hy;
                lv.x = *(ushort*)&lx; lv.y = *(ushort*)&ly;
                *(ushort2*)(ahi + (size_t)node * KPAD + 2 * i) = hv;
                *(ushort2*)(alo + (size_t)node * KPAD + 2 * i) = lv;
            }
        }
    } else {
        #pragma unroll
        for (int j = 0; j < 3; j++) {
            int i = lane + 64 * j;
            if (i < 150) {
                float2 o;
                o.x = fmaxf(acc2[j].x * isel[j] + bias[2 * i],     0.f);
                o.y = fmaxf(acc2[j].y * isel[j] + bias[2 * i + 1], 0.f);
                *(float2*)(fout + (size_t)node * WDIM + 2 * i) = o;
            }
        }
    }
}

// ---------------- host ----------------
static inline size_t align256(size_t x) { return (x + 255) & ~(size_t)255; }

extern "C" void kernel_launch(void* const* d_in, const int* in_sizes, int n_in,
                              void* d_out, int out_size, void* d_ws, size_t ws_size,
                              hipStream_t stream) {
    const int*   x     = (const int*)d_in[0];
    const int*   ei    = (const int*)d_in[1];
    const float* emb   = (const float*)d_in[2];
    const float* Wl0   = (const float*)d_in[3];
    const float* bl0   = (const float*)d_in[4];
    const float* Wr0   = (const float*)d_in[5];
    const float* br0   = (const float*)d_in[6];
    const float* att0  = (const float*)d_in[7];
    const float* bias0 = (const float*)d_in[8];
    const float* Wl    = (const float*)d_in[9];
    const float* bl    = (const float*)d_in[10];
    const float* Wr    = (const float*)d_in[11];
    const float* br    = (const float*)d_in[12];
    const float* att   = (const float*)d_in[13];
    const float* bias  = (const float*)d_in[14];

    char* ws = (char*)d_ws;
    size_t off = 0;
    // order matters for slack-read safety: ahi->alo->xlb->xrb->offsets (ints)
    ushort* ahi   = (ushort*)(ws + off); off = align256(off + (size_t)NODES * KPAD * 2);
    ushort* alo   = (ushort*)(ws + off); off = align256(off + (size_t)NODES * KPAD * 2);
    float* xlb    = (float*)(ws + off);  off = align256(off + (size_t)NODES * WDIM * 4);
    float* xrb    = (float*)(ws + off);  off = align256(off + (size_t)NODES * WDIM * 4);
    int* offsets  = (int*)(ws + off);    off = align256(off + (size_t)(NODES + 1) * 4);
    int* csr_src  = (int*)(ws + off);    off = align256(off + (size_t)ETOT * 4);
    int* counts   = (int*)(ws + off);    off = align256(off + (size_t)NODES * 4);
    int* cursor   = (int*)(ws + off);    off = align256(off + (size_t)NODES * 4);
    bf16x8* bfrag[5];
    bfrag[0] = (bf16x8*)(ws + off); off = align256(off + (size_t)4 * 40 * 2 * 64 * 16);
    for (int i = 1; i < 5; i++) {
        bfrag[i] = (bf16x8*)(ws + off); off = align256(off + (size_t)10 * 40 * 2 * 64 * 16);
    }

    float* out = (float*)d_out;

    // weight fragment pre-splits up-front
    make_bfrag<<<(4 * 40 * 64 + 255) / 256, 256, 0, stream>>>(Wl0, Wr0, bfrag[0], D0, 4);
    for (int i = 0; i < 4; i++)
        make_bfrag<<<(10 * 40 * 64 + 255) / 256, 256, 0, stream>>>(
            Wl + (size_t)i * WDIM * WDIM, Wr + (size_t)i * WDIM * WDIM, bfrag[i + 1], WDIM, 10);

    // CSR build
    hipMemsetAsync(counts, 0, (size_t)NODES * 4, stream);
    hipMemsetAsync(cursor, 0, (size_t)NODES * 4, stream);
    count_edges<<<(ETOT + 255) / 256, 256, 0, stream>>>(ei, counts);
    scan_kernel<<<1, 1024, 0, stream>>>(counts, offsets, NODES);
    scatter_edges<<<(ETOT + 255) / 256, 256, 0, stream>>>(ei, offsets, cursor, csr_src);

    int agg_blocks = (NODES + 3) / 4;

    // layer 0: A = emb with row indirection
    gemm_emb<<<1200, 256, 0, stream>>>(emb, x, bfrag[0], bl0, br0, xlb, xrb, NODES, D0, 4);
    gat_edge_agg<<<agg_blocks, 256, 0, stream>>>(xlb, xrb, offsets, csr_src, att0, bias0,
                                                 nullptr, ahi, alo, 1);

    // layers 1..4
    for (int i = 0; i < 4; i++) {
        int last = (i == 3);
        gemm_frag<<<1200, 256, 0, stream>>>(ahi, alo, bfrag[i + 1], bl + i * WDIM, br + i * WDIM,
                                            xlb, xrb, NODES);
        gat_edge_agg<<<agg_blocks, 256, 0, stream>>>(xlb, xrb, offsets, csr_src,
                                                     att + (size_t)i * WDIM,
                                                     bias + (size_t)i * WDIM,
                                                     last ? out : nullptr, ahi, alo, !last);
    }
}

// Round 9
// 1030.694 us; speedup vs baseline: 1.0035x; 1.0035x over previous
//
#include <hip/hip_runtime.h>

#define NODES   30000
#define E0N     480000
#define ETOT    510000   // E0N + NODES self loops
#define D0      100
#define WDIM    300      // H*F = 3*100
#define NW      600      // dual output width
#define NEG     0.2f
#define G16MAX  1880     // ceil(235*128/16) row-groups in frag buffers

typedef __bf16 bf16x8 __attribute__((ext_vector_type(8)));
typedef float  f32x4  __attribute__((ext_vector_type(4)));

// ---------------- CSR build ----------------
__global__ void count_edges(const int* __restrict__ ei, int* __restrict__ counts) {
    int e = blockIdx.x * 256 + threadIdx.x;
    if (e >= ETOT) return;
    int d = (e < E0N) ? ei[E0N + e] : (e - E0N);
    atomicAdd(&counts[d], 1);
}

__global__ __launch_bounds__(1024) void scan_kernel(const int* __restrict__ counts,
                                                    int* __restrict__ offsets, int n) {
    __shared__ int lds[1024];
    const int CH = 32;
    int t = threadIdx.x;
    int base = t * CH;
    int loc[CH];
    int sum = 0;
    #pragma unroll
    for (int i = 0; i < CH; i++) {
        int v = (base + i < n) ? counts[base + i] : 0;
        loc[i] = sum;
        sum += v;
    }
    lds[t] = sum;
    __syncthreads();
    for (int off = 1; off < 1024; off <<= 1) {
        int v = (t >= off) ? lds[t - off] : 0;
        __syncthreads();
        lds[t] += v;
        __syncthreads();
    }
    int ex = (t == 0) ? 0 : lds[t - 1];
    #pragma unroll
    for (int i = 0; i < CH; i++) {
        int idx = base + i;
        if (idx < n) offsets[idx] = ex + loc[i];
    }
    if (t == 0) offsets[n] = lds[1023];
}

__global__ void scatter_edges(const int* __restrict__ ei, const int* __restrict__ offsets,
                              int* __restrict__ cursor, int* __restrict__ csr_src) {
    int e = blockIdx.x * 256 + threadIdx.x;
    if (e >= ETOT) return;
    int s, d;
    if (e < E0N) { s = ei[e]; d = ei[E0N + e]; }
    else         { s = e - E0N; d = s; }
    int pos = offsets[d] + atomicAdd(&cursor[d], 1);
    csr_src[pos] = s;
}

// ---------------- B fragment pre-split (hi/lo bf16, MFMA-fragment-linear) ----
__global__ void make_bfrag(const float* __restrict__ Bl, const float* __restrict__ Br,
                           bf16x8* __restrict__ out, int K, int ksteps) {
    int t = blockIdx.x * 256 + threadIdx.x;
    int total = ksteps * 40 * 64;
    if (t >= total) return;
    int lane = t & 63;
    int n16  = (t >> 6) % 40;
    int s    = t / (64 * 40);
    int c = n16 * 16 + (lane & 15);
    union { bf16x8 v; __bf16 e[8]; } hi, lo;
    #pragma unroll
    for (int j = 0; j < 8; j++) {
        int k = s * 32 + ((lane >> 4) * 8) + j;
        float x = 0.f;
        if (k < K && c < NW)
            x = (c < WDIM) ? Bl[(size_t)k * WDIM + c] : Br[(size_t)k * WDIM + c - WDIM];
        __bf16 h = (__bf16)x;
        hi.e[j] = h;
        lo.e[j] = (__bf16)(x - (float)h);
    }
    size_t base = ((size_t)(s * 40 + n16) * 2) * 64 + lane;
    out[base]      = hi.v;
    out[base + 64] = lo.v;
}

// ---------------- layer-0 MFMA GEMM: A = emb[xmap[row]] (f32, inline split) ----
__global__ __launch_bounds__(256) void gemm_emb(
    const float* __restrict__ A, const int* __restrict__ xmap,
    const bf16x8* __restrict__ Bfrag,
    const float* __restrict__ bl, const float* __restrict__ br,
    float* __restrict__ Cl, float* __restrict__ Cr,
    int M, int K, int ksteps) {

    __shared__ bf16x8 Alds[8][2][64];
    __shared__ bf16x8 Blds[8][2][64];

    int id = blockIdx.x;
    int mb = (id & 7) + 8 * (id / 40);
    int cb = (id >> 3) % 5;
    if (mb >= 235) return;

    int tid  = threadIdx.x;
    int lane = tid & 63;
    int wid  = tid >> 6;
    int wm = wid >> 1, wn = wid & 1;
    int row0 = mb * 128;

    f32x4 acc[4][4] = {};

    for (int s = 0; s < ksteps; s++) {
        int kt = s * 32;
        #pragma unroll
        for (int u0 = 0; u0 < 2; u0++) {
            int u = u0 * 256 + tid;
            int m16  = u >> 6;
            int slot = u & 63;
            int kh = slot >> 4, rl = slot & 15;
            int gr = row0 + m16 * 16 + rl;
            int gc = kt + kh * 8;
            float4 v0 = make_float4(0.f,0.f,0.f,0.f), v1 = v0;
            if (gr < M) {
                int ar = xmap[gr];
                const float* ap = A + (size_t)ar * K + gc;
                if (gc + 4 <= K) v0 = *(const float4*)ap;
                if (gc + 8 <= K) v1 = *(const float4*)(ap + 4);
            }
            union { bf16x8 v; __bf16 e[8]; } hi, lo;
            const float* xs0 = (const float*)&v0;
            const float* xs1 = (const float*)&v1;
            #pragma unroll
            for (int j = 0; j < 8; j++) {
                float x = (j < 4) ? xs0[j] : xs1[j - 4];
                __bf16 h = (__bf16)x;
                hi.e[j] = h;
                lo.e[j] = (__bf16)(x - (float)h);
            }
            Alds[m16][0][slot] = hi.v;
            Alds[m16][1][slot] = lo.v;
        }
        {
            const float4* bsrc = (const float4*)(Bfrag + ((size_t)(s * 40 + cb * 8) * 2) * 64);
            float4* bdst = (float4*)&Blds[0][0][0];
            #pragma unroll
            for (int c = 0; c < 4; c++)
                bdst[c * 256 + tid] = bsrc[c * 256 + tid];
        }
        __syncthreads();

        bf16x8 af[4][2], bfr[4][2];
        #pragma unroll
        for (int m = 0; m < 4; m++) {
            af[m][0] = Alds[wm * 4 + m][0][lane];
            af[m][1] = Alds[wm * 4 + m][1][lane];
        }
        #pragma unroll
        for (int n = 0; n < 4; n++) {
            bfr[n][0] = Blds[wn * 4 + n][0][lane];
            bfr[n][1] = Blds[wn * 4 + n][1][lane];
        }
        #pragma unroll
        for (int m = 0; m < 4; m++)
            #pragma unroll
            for (int n = 0; n < 4; n++) {
                acc[m][n] = __builtin_amdgcn_mfma_f32_16x16x32_bf16(af[m][1], bfr[n][0], acc[m][n], 0, 0, 0);
                acc[m][n] = __builtin_amdgcn_mfma_f32_16x16x32_bf16(af[m][0], bfr[n][1], acc[m][n], 0, 0, 0);
                acc[m][n] = __builtin_amdgcn_mfma_f32_16x16x32_bf16(af[m][0], bfr[n][0], acc[m][n], 0, 0, 0);
            }
        __syncthreads();
    }

    int r0 = row0 + wm * 64;
    int c0 = cb * 128 + wn * 64;
    #pragma unroll
    for (int m = 0; m < 4; m++)
        #pragma unroll
        for (int n = 0; n < 4; n++) {
            #pragma unroll
            for (int reg = 0; reg < 4; reg++) {
                int gr = r0 + m * 16 + (lane >> 4) * 4 + reg;
                int gc = c0 + n * 16 + (lane & 15);
                if (gr < M && gc < NW) {
                    bool left = gc < WDIM;
                    int cc = left ? gc : gc - WDIM;
                    float v = acc[m][n][reg] + (left ? bl[cc] : br[cc]);
                    (left ? Cl : Cr)[(size_t)gr * WDIM + cc] = v;
                }
            }
        }
}

// ---------------- layers 1-4 MFMA GEMM: A pre-split, fragment-linear layout ----
// A-frag addr of (row gr, col k): ((gr>>4)*40 + (k>>3))*128 + (gr&15)*8 + (k&7)
__global__ __launch_bounds__(256) void gemm_frag(
    const ushort* __restrict__ ahi, const ushort* __restrict__ alo,
    const bf16x8* __restrict__ Bfrag,
    const float* __restrict__ bl, const float* __restrict__ br,
    float* __restrict__ Cl, float* __restrict__ Cr, int M) {

    __shared__ bf16x8 Alds[8][2][64];
    __shared__ bf16x8 Blds[8][2][64];

    int id = blockIdx.x;
    int mb = (id & 7) + 8 * (id / 40);
    int cb = (id >> 3) % 5;
    if (mb >= 235) return;

    int tid  = threadIdx.x;
    int lane = tid & 63;
    int wid  = tid >> 6;
    int wm = wid >> 1, wn = wid & 1;
    int row0 = mb * 128;

    f32x4 acc[4][4] = {};

    for (int s = 0; s < 10; s++) {
        // A stage: contiguous 1KiB per (m16): [g16][s*4+kh][rl][8]
        #pragma unroll
        for (int u0 = 0; u0 < 2; u0++) {
            int u = u0 * 256 + tid;
            int m16  = u >> 6;
            int slot = u & 63;
            size_t off = (((size_t)((row0 >> 4) + m16) * 40 + s * 4 + (slot >> 4)) * 16
                          + (slot & 15)) * 8;
            Alds[m16][0][slot] = *(const bf16x8*)(ahi + off);
            Alds[m16][1][slot] = *(const bf16x8*)(alo + off);
        }
        {
            const float4* bsrc = (const float4*)(Bfrag + ((size_t)(s * 40 + cb * 8) * 2) * 64);
            float4* bdst = (float4*)&Blds[0][0][0];
            #pragma unroll
            for (int c = 0; c < 4; c++)
                bdst[c * 256 + tid] = bsrc[c * 256 + tid];
        }
        __syncthreads();

        bf16x8 af[4][2], bfr[4][2];
        #pragma unroll
        for (int m = 0; m < 4; m++) {
            af[m][0] = Alds[wm * 4 + m][0][lane];
            af[m][1] = Alds[wm * 4 + m][1][lane];
        }
        #pragma unroll
        for (int n = 0; n < 4; n++) {
            bfr[n][0] = Blds[wn * 4 + n][0][lane];
            bfr[n][1] = Blds[wn * 4 + n][1][lane];
        }
        #pragma unroll
        for (int m = 0; m < 4; m++)
            #pragma unroll
            for (int n = 0; n < 4; n++) {
                acc[m][n] = __builtin_amdgcn_mfma_f32_16x16x32_bf16(af[m][1], bfr[n][0], acc[m][n], 0, 0, 0);
                acc[m][n] = __builtin_amdgcn_mfma_f32_16x16x32_bf16(af[m][0], bfr[n][1], acc[m][n], 0, 0, 0);
                acc[m][n] = __builtin_amdgcn_mfma_f32_16x16x32_bf16(af[m][0], bfr[n][0], acc[m][n], 0, 0, 0);
            }
        __syncthreads();
    }

    int r0 = row0 + wm * 64;
    int c0 = cb * 128 + wn * 64;
    #pragma unroll
    for (int m = 0; m < 4; m++)
        #pragma unroll
        for (int n = 0; n < 4; n++) {
            #pragma unroll
            for (int reg = 0; reg < 4; reg++) {
                int gr = r0 + m * 16 + (lane >> 4) * 4 + reg;
                int gc = c0 + n * 16 + (lane & 15);
                if (gr < M && gc < NW) {
                    bool left = gc < WDIM;
                    int cc = left ? gc : gc - WDIM;
                    float v = acc[m][n][reg] + (left ? bl[cc] : br[cc]);
                    (left ? Cl : Cr)[(size_t)gr * WDIM + cc] = v;
                }
            }
        }
}

// ---------------- fused GAT: wave-per-node, 2-edge ILP + 1-deep prefetch ----
#define LOADROW(dst, sid)                                                      \
    {                                                                          \
        const float2* rp_ = (const float2*)(xl + (size_t)(sid) * WDIM);        \
        dst[0] = rp_[lane];                                                    \
        dst[1] = rp_[lane + 64];                                               \
        if (lane < 22) dst[2] = rp_[lane + 128];                               \
        else { dst[2].x = 0.f; dst[2].y = 0.f; }                               \
    }

__global__ __launch_bounds__(256) void gat_edge_agg(
    const float* __restrict__ xl, const float* __restrict__ xr,
    const int* __restrict__ offsets, const int* __restrict__ csr_src,
    const float* __restrict__ att, const float* __restrict__ bias,
    float* __restrict__ fout, ushort* __restrict__ ahi, ushort* __restrict__ alo,
    int write_frag) {
    int node = (blockIdx.x * 256 + threadIdx.x) >> 6;
    int lane = threadIdx.x & 63;
    if (node >= NODES) return;
    int r = lane & 3;
    bool c0 = lane < 50;   // j0: head0 else head1
    bool c1 = lane < 36;   // j1: head1 else head2

    float2 aw2[3], xr2[3];
    const float2* xrrow = (const float2*)(xr + (size_t)node * WDIM);
    #pragma unroll
    for (int j = 0; j < 3; j++) {
        int i = lane + 64 * j;
        if (i < 150) {
            aw2[j].x = att[2 * i]; aw2[j].y = att[2 * i + 1];
            xr2[j] = xrrow[i];
        } else {
            aw2[j].x = 0.f; aw2[j].y = 0.f;
            xr2[j].x = 0.f; xr2[j].y = 0.f;
        }
    }

    float mq = -1e38f, sq = 0.f;
    float2 acc2[3] = {};

    int beg = offsets[node], end = offsets[node + 1];
    int i = beg;
    int sa = csr_src[i];
    int sb = (i + 1 < end) ? csr_src[i + 1] : sa;
    float2 va[3], vb[3];
    LOADROW(va, sa);
    LOADROW(vb, sb);

    while (true) {
        // prefetch next pair's rows before the compute phase
        int inext = i + 2;
        bool have_next = inext < end;
        float2 vna[3], vnb[3];
        if (have_next) {
            int sa_n = csr_src[inext];
            int sb_n = (inext + 1 < end) ? csr_src[inext + 1] : sa_n;
            LOADROW(vna, sa_n);
            LOADROW(vnb, sb_n);
        }

        bool act_b = (i + 1) < end;
        float qa[3], qb[3];
        #pragma unroll
        for (int j = 0; j < 3; j++) {
            float tax = va[j].x + xr2[j].x; tax = fmaxf(tax, NEG * tax);
            float tay = va[j].y + xr2[j].y; tay = fmaxf(tay, NEG * tay);
            float tbx = vb[j].x + xr2[j].x; tbx = fmaxf(tbx, NEG * tbx);
            float tby = vb[j].y + xr2[j].y; tby = fmaxf(tby, NEG * tby);
            qa[j] = tax * aw2[j].x + tay * aw2[j].y;
            qb[j] = tbx * aw2[j].x + tby * aw2[j].y;
        }
        float pa0 = c0 ? qa[0] : 0.f;
        float pa1 = (c0 ? 0.f : qa[0]) + (c1 ? qa[1] : 0.f);
        float pa2 = (c1 ? 0.f : qa[1]) + qa[2];
        float pb0 = c0 ? qb[0] : 0.f;
        float pb1 = (c0 ? 0.f : qb[0]) + (c1 ? qb[1] : 0.f);
        float pb2 = (c1 ? 0.f : qb[1]) + qb[2];

        pa0 += __shfl_xor(pa0, 1, 64); pa1 += __shfl_xor(pa1, 1, 64); pa2 += __shfl_xor(pa2, 1, 64);
        pb0 += __shfl_xor(pb0, 1, 64); pb1 += __shfl_xor(pb1, 1, 64); pb2 += __shfl_xor(pb2, 1, 64);
        pa0 += __shfl_xor(pa0, 2, 64); pa1 += __shfl_xor(pa1, 2, 64); pa2 += __shfl_xor(pa2, 2, 64);
        pb0 += __shfl_xor(pb0, 2, 64); pb1 += __shfl_xor(pb1, 2, 64); pb2 += __shfl_xor(pb2, 2, 64);
        float sqa = (r == 1) ? pa1 : ((r == 2) ? pa2 : pa0);
        float sqb = (r == 1) ? pb1 : ((r == 2) ? pb2 : pb0);
        sqa += __shfl_xor(sqa, 4, 64);  sqb += __shfl_xor(sqb, 4, 64);
        sqa += __shfl_xor(sqa, 8, 64);  sqb += __shfl_xor(sqb, 8, 64);
        sqa += __shfl_xor(sqa, 16, 64); sqb += __shfl_xor(sqb, 16, 64);
        sqa += __shfl_xor(sqa, 32, 64); sqb += __shfl_xor(sqb, 32, 64);
        if (!act_b) sqb = -3e38f;

        float hiq = fmaxf(sqa, sqb);
        if (__any(hiq > mq + 8.f)) {
            float nmq = fmaxf(mq, hiq);
            float eq = __expf(mq - nmq);
            sq *= eq;
            float e0 = __shfl(eq, 0, 64), e1 = __shfl(eq, 1, 64), e2 = __shfl(eq, 2, 64);
            float ej0 = c0 ? e0 : e1, ej1 = c1 ? e1 : e2;
            acc2[0].x *= ej0; acc2[0].y *= ej0;
            acc2[1].x *= ej1; acc2[1].y *= ej1;
            acc2[2].x *= e2;  acc2[2].y *= e2;
            mq = nmq;
        }
        float cqa = __expf(sqa - mq), cqb = __expf(sqb - mq);
        sq += cqa + cqb;
        float ca0 = __shfl(cqa, 0, 64), ca1 = __shfl(cqa, 1, 64), ca2 = __shfl(cqa, 2, 64);
        float cb0 = __shfl(cqb, 0, 64), cb1 = __shfl(cqb, 1, 64), cb2 = __shfl(cqb, 2, 64);
        float caj[3] = { c0 ? ca0 : ca1, c1 ? ca1 : ca2, ca2 };
        float cbj[3] = { c0 ? cb0 : cb1, c1 ? cb1 : cb2, cb2 };
        #pragma unroll
        for (int j = 0; j < 3; j++) {
            acc2[j].x = fmaf(caj[j], va[j].x, acc2[j].x);
            acc2[j].y = fmaf(caj[j], va[j].y, acc2[j].y);
            acc2[j].x = fmaf(cbj[j], vb[j].x, acc2[j].x);
            acc2[j].y = fmaf(cbj[j], vb[j].y, acc2[j].y);
        }

        if (!have_next) break;
        #pragma unroll
        for (int j = 0; j < 3; j++) { va[j] = vna[j]; vb[j] = vnb[j]; }
        i = inext;
    }

    float iq = 1.f / sq;
    float i0 = __shfl(iq, 0, 64), i1 = __shfl(iq, 1, 64), i2 = __shfl(iq, 2, 64);
    float isel[3] = { c0 ? i0 : i1, c1 ? i1 : i2, i2 };

    if (write_frag) {
        #pragma unroll
        for (int j = 0; j < 3; j++) {
            int fi = lane + 64 * j;
            if (fi < 160) {
                float ox = 0.f, oy = 0.f;
                if (fi < 150) {
                    float bx = bias[2 * fi], by = bias[2 * fi + 1];
                    ox = fmaxf(acc2[j].x * isel[j] + bx, 0.f);
                    oy = fmaxf(acc2[j].y * isel[j] + by, 0.f);
                }
                __bf16 hx = (__bf16)ox, hy = (__bf16)oy;
                __bf16 lx = (__bf16)(ox - (float)hx), ly = (__bf16)(oy - (float)hy);
                ushort2 hv, lv;
                hv.x = *(ushort*)&hx; hv.y = *(ushort*)&hy;
                lv.x = *(ushort*)&lx; lv.y = *(ushort*)&ly;
                int k = 2 * fi;
                size_t off = (((size_t)(node >> 4) * 40 + (k >> 3)) * 16 + (node & 15)) * 8
                             + (k & 7);
                *(ushort2*)(ahi + off) = hv;
                *(ushort2*)(alo + off) = lv;
            }
        }
    } else {
        #pragma unroll
        for (int j = 0; j < 3; j++) {
            int fi = lane + 64 * j;
            if (fi < 150) {
                float2 o;
                o.x = fmaxf(acc2[j].x * isel[j] + bias[2 * fi],     0.f);
                o.y = fmaxf(acc2[j].y * isel[j] + bias[2 * fi + 1], 0.f);
                *(float2*)(fout + (size_t)node * WDIM + 2 * fi) = o;
            }
        }
    }
}

// ---------------- host ----------------
static inline size_t align256(size_t x) { return (x + 255) & ~(size_t)255; }

extern "C" void kernel_launch(void* const* d_in, const int* in_sizes, int n_in,
                              void* d_out, int out_size, void* d_ws, size_t ws_size,
                              hipStream_t stream) {
    const int*   x     = (const int*)d_in[0];
    const int*   ei    = (const int*)d_in[1];
    const float* emb   = (const float*)d_in[2];
    const float* Wl0   = (const float*)d_in[3];
    const float* bl0   = (const float*)d_in[4];
    const float* Wr0   = (const float*)d_in[5];
    const float* br0   = (const float*)d_in[6];
    const float* att0  = (const float*)d_in[7];
    const float* bias0 = (const float*)d_in[8];
    const float* Wl    = (const float*)d_in[9];
    const float* bl    = (const float*)d_in[10];
    const float* Wr    = (const float*)d_in[11];
    const float* br    = (const float*)d_in[12];
    const float* att   = (const float*)d_in[13];
    const float* bias  = (const float*)d_in[14];

    char* ws = (char*)d_ws;
    size_t off = 0;
    size_t fragsz = (size_t)G16MAX * 40 * 16 * 8;   // ushorts
    ushort* ahi   = (ushort*)(ws + off); off = align256(off + fragsz * 2);
    ushort* alo   = (ushort*)(ws + off); off = align256(off + fragsz * 2);
    float* xlb    = (float*)(ws + off);  off = align256(off + (size_t)NODES * WDIM * 4);
    float* xrb    = (float*)(ws + off);  off = align256(off + (size_t)NODES * WDIM * 4);
    int* offsets  = (int*)(ws + off);    off = align256(off + (size_t)(NODES + 1) * 4);
    int* csr_src  = (int*)(ws + off);    off = align256(off + (size_t)ETOT * 4);
    int* counts   = (int*)(ws + off);    off = align256(off + (size_t)NODES * 4);
    int* cursor   = (int*)(ws + off);    off = align256(off + (size_t)NODES * 4);
    bf16x8* bfrag[5];
    bfrag[0] = (bf16x8*)(ws + off); off = align256(off + (size_t)4 * 40 * 2 * 64 * 16);
    for (int i = 1; i < 5; i++) {
        bfrag[i] = (bf16x8*)(ws + off); off = align256(off + (size_t)10 * 40 * 2 * 64 * 16);
    }

    float* out = (float*)d_out;

    // weight fragment pre-splits up-front
    make_bfrag<<<(4 * 40 * 64 + 255) / 256, 256, 0, stream>>>(Wl0, Wr0, bfrag[0], D0, 4);
    for (int i = 0; i < 4; i++)
        make_bfrag<<<(10 * 40 * 64 + 255) / 256, 256, 0, stream>>>(
            Wl + (size_t)i * WDIM * WDIM, Wr + (size_t)i * WDIM * WDIM, bfrag[i + 1], WDIM, 10);

    // CSR build
    hipMemsetAsync(counts, 0, (size_t)NODES * 4, stream);
    hipMemsetAsync(cursor, 0, (size_t)NODES * 4, stream);
    count_edges<<<(ETOT + 255) / 256, 256, 0, stream>>>(ei, counts);
    scan_kernel<<<1, 1024, 0, stream>>>(counts, offsets, NODES);
    scatter_edges<<<(ETOT + 255) / 256, 256, 0, stream>>>(ei, offsets, cursor, csr_src);

    int agg_blocks = (NODES + 3) / 4;

    // layer 0: A = emb with row indirection
    gemm_emb<<<1200, 256, 0, stream>>>(emb, x, bfrag[0], bl0, br0, xlb, xrb, NODES, D0, 4);
    gat_edge_agg<<<agg_blocks, 256, 0, stream>>>(xlb, xrb, offsets, csr_src, att0, bias0,
                                                 nullptr, ahi, alo, 1);

    // layers 1..4
    for (int i = 0; i < 4; i++) {
        int last = (i == 3);
        gemm_frag<<<1200, 256, 0, stream>>>(ahi, alo, bfrag[i + 1], bl + i * WDIM, br + i * WDIM,
                                            xlb, xrb, NODES);
        gat_edge_agg<<<agg_blocks, 256, 0, stream>>>(xlb, xrb, offsets, csr_src,
                                                     att + (size_t)i * WDIM,
                                                     bias + (size_t)i * WDIM,
                                                     last ? out : nullptr, ahi, alo, !last);
    }
}

// Round 10
// 889.218 us; speedup vs baseline: 1.1631x; 1.1591x over previous
//
#include <hip/hip_runtime.h>

#define NODES   30000
#define E0N     480000
#define ETOT    510000   // E0N + NODES self loops
#define D0      100
#define WDIM    300      // H*F = 3*100
#define NW      600      // dual output width
#define NEG     0.2f

typedef __bf16 bf16x8 __attribute__((ext_vector_type(8)));
typedef float  f32x4  __attribute__((ext_vector_type(4)));

// ---------------- CSR build ----------------
__global__ void count_edges(const int* __restrict__ ei, int* __restrict__ counts) {
    int e = blockIdx.x * 256 + threadIdx.x;
    if (e >= ETOT) return;
    int d = (e < E0N) ? ei[E0N + e] : (e - E0N);
    atomicAdd(&counts[d], 1);
}

__global__ __launch_bounds__(1024) void scan_kernel(const int* __restrict__ counts,
                                                    int* __restrict__ offsets, int n) {
    __shared__ int lds[1024];
    const int CH = 32;
    int t = threadIdx.x;
    int base = t * CH;
    int loc[CH];
    int sum = 0;
    #pragma unroll
    for (int i = 0; i < CH; i++) {
        int v = (base + i < n) ? counts[base + i] : 0;
        loc[i] = sum;
        sum += v;
    }
    lds[t] = sum;
    __syncthreads();
    for (int off = 1; off < 1024; off <<= 1) {
        int v = (t >= off) ? lds[t - off] : 0;
        __syncthreads();
        lds[t] += v;
        __syncthreads();
    }
    int ex = (t == 0) ? 0 : lds[t - 1];
    #pragma unroll
    for (int i = 0; i < CH; i++) {
        int idx = base + i;
        if (idx < n) offsets[idx] = ex + loc[i];
    }
    if (t == 0) offsets[n] = lds[1023];
}

__global__ void scatter_edges(const int* __restrict__ ei, const int* __restrict__ offsets,
                              int* __restrict__ cursor, int* __restrict__ csr_src) {
    int e = blockIdx.x * 256 + threadIdx.x;
    if (e >= ETOT) return;
    int s, d;
    if (e < E0N) { s = ei[e]; d = ei[E0N + e]; }
    else         { s = e - E0N; d = s; }
    int pos = offsets[d] + atomicAdd(&cursor[d], 1);
    csr_src[pos] = s;
}

// ---------------- B fragment pre-split (hi/lo bf16, MFMA-fragment-linear) ----
__global__ void make_bfrag(const float* __restrict__ Bl, const float* __restrict__ Br,
                           bf16x8* __restrict__ out, int K, int ksteps) {
    int t = blockIdx.x * 256 + threadIdx.x;
    int total = ksteps * 40 * 64;
    if (t >= total) return;
    int lane = t & 63;
    int n16  = (t >> 6) % 40;
    int s    = t / (64 * 40);
    int c = n16 * 16 + (lane & 15);
    union { bf16x8 v; __bf16 e[8]; } hi, lo;
    #pragma unroll
    for (int j = 0; j < 8; j++) {
        int k = s * 32 + ((lane >> 4) * 8) + j;
        float x = 0.f;
        if (k < K && c < NW)
            x = (c < WDIM) ? Bl[(size_t)k * WDIM + c] : Br[(size_t)k * WDIM + c - WDIM];
        __bf16 h = (__bf16)x;
        hi.e[j] = h;
        lo.e[j] = (__bf16)(x - (float)h);
    }
    size_t base = ((size_t)(s * 40 + n16) * 2) * 64 + lane;
    out[base]      = hi.v;
    out[base + 64] = lo.v;
}

// ---------------- MFMA dual GEMM: [Cl|Cr] = A @ [Bl|Br] + [bl|br] ----------
// split-bf16 hi/lo, 3 cross-product MFMAs (ll dropped), f32 accumulate.
// use_map: A-row indirection (layer-0 embedding fold-in).
__global__ __launch_bounds__(256) void gemm_mfma(
    const float* __restrict__ A, const int* __restrict__ xmap, int use_map,
    const bf16x8* __restrict__ Bfrag,
    const float* __restrict__ bl, const float* __restrict__ br,
    float* __restrict__ Cl, float* __restrict__ Cr,
    int M, int K, int ksteps) {

    __shared__ bf16x8 Alds[8][2][64];
    __shared__ bf16x8 Blds[8][2][64];

    int id = blockIdx.x;
    int mb = (id & 7) + 8 * (id / 40);
    int cb = (id >> 3) % 5;
    if (mb >= 235) return;

    int tid  = threadIdx.x;
    int lane = tid & 63;
    int wid  = tid >> 6;
    int wm = wid >> 1, wn = wid & 1;
    int row0 = mb * 128;

    f32x4 acc[4][4] = {};

    for (int s = 0; s < ksteps; s++) {
        int kt = s * 32;
        #pragma unroll
        for (int u0 = 0; u0 < 2; u0++) {
            int u = u0 * 256 + tid;
            int m16  = u >> 6;
            int slot = u & 63;
            int kh = slot >> 4, rl = slot & 15;
            int gr = row0 + m16 * 16 + rl;
            int gc = kt + kh * 8;
            float4 v0 = make_float4(0.f,0.f,0.f,0.f), v1 = v0;
            if (gr < M) {
                int ar = use_map ? xmap[gr] : gr;
                const float* ap = A + (size_t)ar * K + gc;
                if (gc + 4 <= K) v0 = *(const float4*)ap;
                if (gc + 8 <= K) v1 = *(const float4*)(ap + 4);
            }
            union { bf16x8 v; __bf16 e[8]; } hi, lo;
            const float* xs0 = (const float*)&v0;
            const float* xs1 = (const float*)&v1;
            #pragma unroll
            for (int j = 0; j < 8; j++) {
                float x = (j < 4) ? xs0[j] : xs1[j - 4];
                __bf16 h = (__bf16)x;
                hi.e[j] = h;
                lo.e[j] = (__bf16)(x - (float)h);
            }
            Alds[m16][0][slot] = hi.v;
            Alds[m16][1][slot] = lo.v;
        }
        {
            const float4* bsrc = (const float4*)(Bfrag + ((size_t)(s * 40 + cb * 8) * 2) * 64);
            float4* bdst = (float4*)&Blds[0][0][0];
            #pragma unroll
            for (int c = 0; c < 4; c++)
                bdst[c * 256 + tid] = bsrc[c * 256 + tid];
        }
        __syncthreads();

        bf16x8 af[4][2], bfr[4][2];
        #pragma unroll
        for (int m = 0; m < 4; m++) {
            af[m][0] = Alds[wm * 4 + m][0][lane];
            af[m][1] = Alds[wm * 4 + m][1][lane];
        }
        #pragma unroll
        for (int n = 0; n < 4; n++) {
            bfr[n][0] = Blds[wn * 4 + n][0][lane];
            bfr[n][1] = Blds[wn * 4 + n][1][lane];
        }
        #pragma unroll
        for (int m = 0; m < 4; m++)
            #pragma unroll
            for (int n = 0; n < 4; n++) {
                acc[m][n] = __builtin_amdgcn_mfma_f32_16x16x32_bf16(af[m][1], bfr[n][0], acc[m][n], 0, 0, 0);
                acc[m][n] = __builtin_amdgcn_mfma_f32_16x16x32_bf16(af[m][0], bfr[n][1], acc[m][n], 0, 0, 0);
                acc[m][n] = __builtin_amdgcn_mfma_f32_16x16x32_bf16(af[m][0], bfr[n][0], acc[m][n], 0, 0, 0);
            }
        __syncthreads();
    }

    int r0 = row0 + wm * 64;
    int c0 = cb * 128 + wn * 64;
    #pragma unroll
    for (int m = 0; m < 4; m++)
        #pragma unroll
        for (int n = 0; n < 4; n++) {
            #pragma unroll
            for (int reg = 0; reg < 4; reg++) {
                int gr = r0 + m * 16 + (lane >> 4) * 4 + reg;
                int gc = c0 + n * 16 + (lane & 15);
                if (gr < M && gc < NW) {
                    bool left = gc < WDIM;
                    int cc = left ? gc : gc - WDIM;
                    float v = acc[m][n][reg] + (left ? bl[cc] : br[cc]);
                    (left ? Cl : Cr)[(size_t)gr * WDIM + cc] = v;
                }
            }
        }
}

// ---------------- fused GAT: 2 waves per node, 2-edge ILP, LDS merge ----
// Block = 4 waves = 2 nodes. Wave sub∈{0,1} handles half the node's edges.
// Softmax state packed by lane residue r=lane&3 (r=0:h0 r=1:h1 r=2:h2).
__global__ __launch_bounds__(256) void gat_edge_agg(
    const float* __restrict__ xl, const float* __restrict__ xr,
    const int* __restrict__ offsets, const int* __restrict__ csr_src,
    const float* __restrict__ att, const float* __restrict__ bias,
    float* __restrict__ fout) {
    __shared__ float st[4][64][8];
    int wid  = threadIdx.x >> 6;
    int lane = threadIdx.x & 63;
    int node = blockIdx.x * 2 + (wid >> 1);   // NODES even: always valid
    int sub  = wid & 1;
    int r = lane & 3;
    bool c0 = lane < 50;   // j0: head0 else head1
    bool c1 = lane < 36;   // j1: head1 else head2

    float2 aw2[3], xr2[3];
    const float2* xrrow = (const float2*)(xr + (size_t)node * WDIM);
    #pragma unroll
    for (int j = 0; j < 3; j++) {
        int i = lane + 64 * j;
        if (i < 150) {
            aw2[j].x = att[2 * i]; aw2[j].y = att[2 * i + 1];
            xr2[j] = xrrow[i];
        } else {
            aw2[j].x = 0.f; aw2[j].y = 0.f;
            xr2[j].x = 0.f; xr2[j].y = 0.f;
        }
    }

    float mq = -1e38f, sq = 0.f;
    float2 acc2[3] = {};

    int beg = offsets[node], end = offsets[node + 1];
    int half = (end - beg + 1) >> 1;
    int lo = beg + sub * half;
    int hi = sub ? end : beg + half;

    for (int i = lo; i < hi; i += 2) {
        bool act_b = (i + 1) < hi;
        int sa = csr_src[i];
        int sb = csr_src[act_b ? i + 1 : i];
        const float2* ra = (const float2*)(xl + (size_t)sa * WDIM);
        const float2* rb = (const float2*)(xl + (size_t)sb * WDIM);
        float2 va[3], vb[3];
        va[0] = ra[lane];      vb[0] = rb[lane];
        va[1] = ra[lane + 64]; vb[1] = rb[lane + 64];
        if (lane < 22) { va[2] = ra[lane + 128]; vb[2] = rb[lane + 128]; }
        else { va[2].x = va[2].y = vb[2].x = vb[2].y = 0.f; }

        float qa[3], qb[3];
        #pragma unroll
        for (int j = 0; j < 3; j++) {
            float tax = va[j].x + xr2[j].x; tax = fmaxf(tax, NEG * tax);
            float tay = va[j].y + xr2[j].y; tay = fmaxf(tay, NEG * tay);
            float tbx = vb[j].x + xr2[j].x; tbx = fmaxf(tbx, NEG * tbx);
            float tby = vb[j].y + xr2[j].y; tby = fmaxf(tby, NEG * tby);
            qa[j] = tax * aw2[j].x + tay * aw2[j].y;
            qb[j] = tbx * aw2[j].x + tby * aw2[j].y;
        }
        float pa0 = c0 ? qa[0] : 0.f;
        float pa1 = (c0 ? 0.f : qa[0]) + (c1 ? qa[1] : 0.f);
        float pa2 = (c1 ? 0.f : qa[1]) + qa[2];
        float pb0 = c0 ? qb[0] : 0.f;
        float pb1 = (c0 ? 0.f : qb[0]) + (c1 ? qb[1] : 0.f);
        float pb2 = (c1 ? 0.f : qb[1]) + qb[2];

        pa0 += __shfl_xor(pa0, 1, 64); pa1 += __shfl_xor(pa1, 1, 64); pa2 += __shfl_xor(pa2, 1, 64);
        pb0 += __shfl_xor(pb0, 1, 64); pb1 += __shfl_xor(pb1, 1, 64); pb2 += __shfl_xor(pb2, 1, 64);
        pa0 += __shfl_xor(pa0, 2, 64); pa1 += __shfl_xor(pa1, 2, 64); pa2 += __shfl_xor(pa2, 2, 64);
        pb0 += __shfl_xor(pb0, 2, 64); pb1 += __shfl_xor(pb1, 2, 64); pb2 += __shfl_xor(pb2, 2, 64);
        float sqa = (r == 1) ? pa1 : ((r == 2) ? pa2 : pa0);
        float sqb = (r == 1) ? pb1 : ((r == 2) ? pb2 : pb0);
        sqa += __shfl_xor(sqa, 4, 64);  sqb += __shfl_xor(sqb, 4, 64);
        sqa += __shfl_xor(sqa, 8, 64);  sqb += __shfl_xor(sqb, 8, 64);
        sqa += __shfl_xor(sqa, 16, 64); sqb += __shfl_xor(sqb, 16, 64);
        sqa += __shfl_xor(sqa, 32, 64); sqb += __shfl_xor(sqb, 32, 64);
        if (!act_b) sqb = -3e38f;

        float hiq = fmaxf(sqa, sqb);
        if (__any(hiq > mq + 8.f)) {
            float nmq = fmaxf(mq, hiq);
            float eq = __expf(mq - nmq);
            sq *= eq;
            float e0 = __shfl(eq, 0, 64), e1 = __shfl(eq, 1, 64), e2 = __shfl(eq, 2, 64);
            float ej0 = c0 ? e0 : e1, ej1 = c1 ? e1 : e2;
            acc2[0].x *= ej0; acc2[0].y *= ej0;
            acc2[1].x *= ej1; acc2[1].y *= ej1;
            acc2[2].x *= e2;  acc2[2].y *= e2;
            mq = nmq;
        }
        float cqa = __expf(sqa - mq), cqb = __expf(sqb - mq);
        sq += cqa + cqb;
        float ca0 = __shfl(cqa, 0, 64), ca1 = __shfl(cqa, 1, 64), ca2 = __shfl(cqa, 2, 64);
        float cb0 = __shfl(cqb, 0, 64), cb1 = __shfl(cqb, 1, 64), cb2 = __shfl(cqb, 2, 64);
        float caj[3] = { c0 ? ca0 : ca1, c1 ? ca1 : ca2, ca2 };
        float cbj[3] = { c0 ? cb0 : cb1, c1 ? cb1 : cb2, cb2 };
        #pragma unroll
        for (int j = 0; j < 3; j++) {
            acc2[j].x = fmaf(caj[j], va[j].x, acc2[j].x);
            acc2[j].y = fmaf(caj[j], va[j].y, acc2[j].y);
            acc2[j].x = fmaf(cbj[j], vb[j].x, acc2[j].x);
            acc2[j].y = fmaf(cbj[j], vb[j].y, acc2[j].y);
        }
    }

    // publish partial state
    st[wid][lane][0] = mq;
    st[wid][lane][1] = sq;
    st[wid][lane][2] = acc2[0].x; st[wid][lane][3] = acc2[0].y;
    st[wid][lane][4] = acc2[1].x; st[wid][lane][5] = acc2[1].y;
    st[wid][lane][6] = acc2[2].x; st[wid][lane][7] = acc2[2].y;
    __syncthreads();
    if (sub) return;

    // exact merge with partner wave
    float m1 = st[wid ^ 1][lane][0];
    float s1 = st[wid ^ 1][lane][1];
    float2 o1[3];
    o1[0].x = st[wid ^ 1][lane][2]; o1[0].y = st[wid ^ 1][lane][3];
    o1[1].x = st[wid ^ 1][lane][4]; o1[1].y = st[wid ^ 1][lane][5];
    o1[2].x = st[wid ^ 1][lane][6]; o1[2].y = st[wid ^ 1][lane][7];

    float M  = fmaxf(mq, m1);
    float ea = __expf(mq - M), eb = __expf(m1 - M);
    float sF = sq * ea + s1 * eb;
    float iq = 1.f / sF;
    float ea0 = __shfl(ea, 0, 64), ea1 = __shfl(ea, 1, 64), ea2 = __shfl(ea, 2, 64);
    float eb0 = __shfl(eb, 0, 64), eb1 = __shfl(eb, 1, 64), eb2 = __shfl(eb, 2, 64);
    float i0  = __shfl(iq, 0, 64), i1  = __shfl(iq, 1, 64), i2  = __shfl(iq, 2, 64);
    float eaj[3]  = { c0 ? ea0 : ea1, c1 ? ea1 : ea2, ea2 };
    float ebj[3]  = { c0 ? eb0 : eb1, c1 ? eb1 : eb2, eb2 };
    float isel[3] = { c0 ? i0 : i1,  c1 ? i1 : i2,  i2 };

    #pragma unroll
    for (int j = 0; j < 3; j++) {
        int fi = lane + 64 * j;
        if (fi < 150) {
            float ax = acc2[j].x * eaj[j] + o1[j].x * ebj[j];
            float ay = acc2[j].y * eaj[j] + o1[j].y * ebj[j];
            float2 o;
            o.x = fmaxf(ax * isel[j] + bias[2 * fi],     0.f);
            o.y = fmaxf(ay * isel[j] + bias[2 * fi + 1], 0.f);
            *(float2*)(fout + (size_t)node * WDIM + 2 * fi) = o;
        }
    }
}

// ---------------- host ----------------
static inline size_t align256(size_t x) { return (x + 255) & ~(size_t)255; }

extern "C" void kernel_launch(void* const* d_in, const int* in_sizes, int n_in,
                              void* d_out, int out_size, void* d_ws, size_t ws_size,
                              hipStream_t stream) {
    const int*   x     = (const int*)d_in[0];
    const int*   ei    = (const int*)d_in[1];
    const float* emb   = (const float*)d_in[2];
    const float* Wl0   = (const float*)d_in[3];
    const float* bl0   = (const float*)d_in[4];
    const float* Wr0   = (const float*)d_in[5];
    const float* br0   = (const float*)d_in[6];
    const float* att0  = (const float*)d_in[7];
    const float* bias0 = (const float*)d_in[8];
    const float* Wl    = (const float*)d_in[9];
    const float* bl    = (const float*)d_in[10];
    const float* Wr    = (const float*)d_in[11];
    const float* br    = (const float*)d_in[12];
    const float* att   = (const float*)d_in[13];
    const float* bias  = (const float*)d_in[14];

    char* ws = (char*)d_ws;
    size_t off = 0;
    float* h      = (float*)(ws + off); off = align256(off + (size_t)NODES * WDIM * 4);
    float* xlb    = (float*)(ws + off); off = align256(off + (size_t)NODES * WDIM * 4);
    float* xrb    = (float*)(ws + off); off = align256(off + (size_t)NODES * WDIM * 4);
    int* counts   = (int*)(ws + off);   off = align256(off + (size_t)NODES * 4);
    int* cursor   = (int*)(ws + off);   off = align256(off + (size_t)NODES * 4);
    int* offsets  = (int*)(ws + off);   off = align256(off + (size_t)(NODES + 1) * 4);
    int* csr_src  = (int*)(ws + off);   off = align256(off + (size_t)ETOT * 4);
    bf16x8* bfrag[5];
    bfrag[0] = (bf16x8*)(ws + off); off = align256(off + (size_t)4 * 40 * 2 * 64 * 16);
    for (int i = 1; i < 5; i++) {
        bfrag[i] = (bf16x8*)(ws + off); off = align256(off + (size_t)10 * 40 * 2 * 64 * 16);
    }

    float* out = (float*)d_out;

    // weight fragment pre-splits up-front
    make_bfrag<<<(4 * 40 * 64 + 255) / 256, 256, 0, stream>>>(Wl0, Wr0, bfrag[0], D0, 4);
    for (int i = 0; i < 4; i++)
        make_bfrag<<<(10 * 40 * 64 + 255) / 256, 256, 0, stream>>>(
            Wl + (size_t)i * WDIM * WDIM, Wr + (size_t)i * WDIM * WDIM, bfrag[i + 1], WDIM, 10);

    // CSR build
    hipMemsetAsync(counts, 0, (size_t)NODES * 4, stream);
    hipMemsetAsync(cursor, 0, (size_t)NODES * 4, stream);
    count_edges<<<(ETOT + 255) / 256, 256, 0, stream>>>(ei, counts);
    scan_kernel<<<1, 1024, 0, stream>>>(counts, offsets, NODES);
    scatter_edges<<<(ETOT + 255) / 256, 256, 0, stream>>>(ei, offsets, cursor, csr_src);

    int agg_blocks = NODES / 2;   // 2 nodes per block (NODES even)

    // layer 0: A = emb with row indirection
    gemm_mfma<<<1200, 256, 0, stream>>>(emb, x, 1, bfrag[0], bl0, br0, xlb, xrb, NODES, D0, 4);
    gat_edge_agg<<<agg_blocks, 256, 0, stream>>>(xlb, xrb, offsets, csr_src, att0, bias0, h);

    // layers 1..4
    for (int i = 0; i < 4; i++) {
        float* dst = (i == 3) ? out : h;
        gemm_mfma<<<1200, 256, 0, stream>>>(h, nullptr, 0, bfrag[i + 1], bl + i * WDIM, br + i * WDIM,
                                            xlb, xrb, NODES, WDIM, 10);
        gat_edge_agg<<<agg_blocks, 256, 0, stream>>>(xlb, xrb, offsets, csr_src,
                                                     att + (size_t)i * WDIM,
                                                     bias + (size_t)i * WDIM, dst);
    }
}